// Round 1
// baseline (193.383 us; speedup 1.0000x reference)
//
#include <hip/hip_runtime.h>

#define S 256
#define NDIAG 511          // diagonals 0..510
#define BIGF 1000000000.0f

// One block per batch. Thread i owns row i. Diagonal k holds cells (i, k-i).
// D[i][j] = C[i][j] + softmin(D[i-1][j], D[i][j-1], D[i-1][j-1]).
// In diagonal coords at step k:
//   a = D[i][j-1]   = my value from diag k-1 (register)
//   b = D[i-1][j]   = neighbor's value from diag k-1 (LDS p1[i-1])
//   c = D[i-1][j-1] = neighbor's value from diag k-2 (LDS p2[i-1])
// Triple-buffered LDS diagonals -> one __syncthreads per diagonal.
__global__ __launch_bounds__(256) void dp_softmin_kernel(const float* __restrict__ C,
                                                         float* __restrict__ out) {
    const int b = blockIdx.x;
    const int i = threadIdx.x;

    __shared__ float buf0[S], buf1[S], buf2[S];

    buf0[i] = BIGF;
    buf1[i] = BIGF;
    buf2[i] = BIGF;

    // C[b][i][k-i] = base + i*256 + (k-i) = base + i*255 + k
    const float* Cb = C + ((size_t)b << 16) + (size_t)i * 255;

    float my_d1 = BIGF;   // my value on the previous diagonal (D[i][j-1])

    if (i == 0) {
        my_d1 = Cb[0];    // seed D[0][0] = C[0][0]
        buf0[0] = my_d1;
    }
    __syncthreads();

    float* pw = buf1;   // write slot (diag k)
    float* p1 = buf0;   // diag k-1
    float* p2 = buf2;   // diag k-2 (starts as all-BIG = diag -1)

    // prefetched C value for my next valid diagonal
    float cnext = Cb[i == 0 ? 1 : i];

    for (int k = 1; k < NDIAG; ++k) {
        const bool valid = (i <= k) && (k - i < S);
        if (valid) {
            float c = cnext;
            if (k - i < S - 1) cnext = Cb[k + 1];   // prefetch next diagonal's C
            float a = my_d1;
            float bb = (i > 0) ? p1[i - 1] : BIGF;
            float cc = (i > 0) ? p2[i - 1] : BIGF;
            float m = fminf(fminf(a, bb), cc);
            float s = __expf(m - a) + __expf(m - bb) + __expf(m - cc);
            float d = c + m - __logf(s);
            pw[i] = d;
            my_d1 = d;
        }
        __syncthreads();
        float* t = p2; p2 = p1; p1 = pw; pw = t;
    }

    // Thread 255's last computed value (diag 510) is D[255][255].
    if (i == S - 1) out[b] = my_d1;
}

extern "C" void kernel_launch(void* const* d_in, const int* in_sizes, int n_in,
                              void* d_out, int out_size, void* d_ws, size_t ws_size,
                              hipStream_t stream) {
    const float* C = (const float*)d_in[0];
    float* out = (float*)d_out;
    dp_softmin_kernel<<<512, 256, 0, stream>>>(C, out);
}

// Round 4
// 143.962 us; speedup vs baseline: 1.3433x; 1.3433x over previous
//
#include <hip/hip_runtime.h>

#define S 256
#define BIGE 1.0e9f              // "BIG" kept directly in E(log2)-domain; only role is exp2(m-x) -> 0
#define L2E 1.44269504088896340736f   // log2(e)
#define LN2 0.69314718055994530942f

// Raw HW transcendentals: v_exp_f32 computes 2^x, v_log_f32 computes log2(x).
#define EXP2F(x) __builtin_amdgcn_exp2f(x)
#define LOG2F(x) __builtin_amdgcn_logf(x)

// One wave (64 threads) per batch. Thread t owns rows 4t..4t+3.
// DP kept in E-domain: E = D * log2(e), so softmin uses raw v_exp_f32/v_log_f32:
//   E[i][j] = C[i][j]*L2E + mE - log2( 2^(mE-aE) + 2^(mE-bE) + 2^(mE-cE) ),  mE = min3.
// Cross-thread neighbor (row 4t-1) comes via __shfl_up — no barriers, no LDS.
// C per row is consumed through float4 quad buffers (cur4/nxt4), one vector
// load per thread per diagonal (the row r == k%4 has j%4==0), prefetched 4
// diagonals ahead. Diagonal loop unrolled x4 so every array index is
// compile-time (keeps cur4/nxt4/d1/d2 in registers, no scratch).

__device__ __forceinline__ float compf(const float4& v, int c) {
    return c == 0 ? v.x : c == 1 ? v.y : c == 2 ? v.z : v.w;
}

template <int P>
__device__ __forceinline__ void step(int kk, int t, const float* __restrict__ Cb,
                                     float4 cur4[4], float4 nxt4[4],
                                     float d1[4], float d2[4]) {
    // neighbor row 4t-1 previous-diag values from thread t-1
    float pd1 = __shfl_up(d1[3], 1);
    float pd2 = __shfl_up(d2[3], 1);
    if (t == 0) { pd1 = BIGE; pd2 = BIGE; }

    // designated row P has j % 4 == 0 this diagonal: rotate quad + prefetch next
    int jp = kk - 4 * t - P;
    if (jp > 0 && jp < S) cur4[P] = nxt4[P];
    if (jp >= 0 && jp < S - 4)
        nxt4[P] = *(const float4*)(Cb + (((size_t)(4 * t + P)) << 8) + jp + 4);

    float dn[4];
#pragma unroll
    for (int r = 0; r < 4; ++r) {
        int j = kk - 4 * t - r;
        bool valid = (j >= 0) && (j < S);
        float a  = d1[r];
        float bb = (r == 0) ? pd1 : d1[r - 1];
        float cc = (r == 0) ? pd2 : d2[r - 1];
        float m  = fminf(fminf(a, bb), cc);
        float sm = EXP2F(m - a) + EXP2F(m - bb) + EXP2F(m - cc);
        float cE = compf(cur4[r], (P - r) & 3) * L2E;
        float v  = cE + m - LOG2F(sm);
        dn[r] = valid ? v : BIGE;
    }
#pragma unroll
    for (int r = 0; r < 4; ++r) { d2[r] = d1[r]; d1[r] = dn[r]; }
}

__global__ __launch_bounds__(64) void dp_softmin_wave(const float* __restrict__ C,
                                                      float* __restrict__ out) {
    const int b = blockIdx.x;
    const int t = threadIdx.x;          // lane 0..63
    const float* Cb = C + ((size_t)b << 16);

    float4 cur4[4], nxt4[4];
    float d1[4], d2[4];

#pragma unroll
    for (int r = 0; r < 4; ++r) {
        cur4[r] = *(const float4*)(Cb + (((size_t)(4 * t + r)) << 8));  // quad j=0..3
        d1[r] = BIGE;
        d2[r] = BIGE;
        nxt4[r] = cur4[r];   // init (overwritten before any real use)
    }
    // seed: D[0][0] = C[0][0]  (diag k=0)
    if (t == 0) {
        d1[0] = cur4[0].x * L2E;
        // row 0's designated step kk=0 isn't executed below: do its prefetch here
        nxt4[0] = *(const float4*)(Cb + 4);   // row 0, quad j=4..7
    }

    // diagonals k = 1 .. 510, phase P = k % 4 is compile-time per call
    step<1>(1, t, Cb, cur4, nxt4, d1, d2);
    step<2>(2, t, Cb, cur4, nxt4, d1, d2);
    step<3>(3, t, Cb, cur4, nxt4, d1, d2);
    for (int kb = 4; kb <= 504; kb += 4) {
        step<0>(kb + 0, t, Cb, cur4, nxt4, d1, d2);
        step<1>(kb + 1, t, Cb, cur4, nxt4, d1, d2);
        step<2>(kb + 2, t, Cb, cur4, nxt4, d1, d2);
        step<3>(kb + 3, t, Cb, cur4, nxt4, d1, d2);
    }
    step<0>(508, t, Cb, cur4, nxt4, d1, d2);
    step<1>(509, t, Cb, cur4, nxt4, d1, d2);
    step<2>(510, t, Cb, cur4, nxt4, d1, d2);

    // D[255][255] lives in thread 63's d1[3] (E-domain)
    if (t == 63) out[b] = d1[3] * LN2;
}

extern "C" void kernel_launch(void* const* d_in, const int* in_sizes, int n_in,
                              void* d_out, int out_size, void* d_ws, size_t ws_size,
                              hipStream_t stream) {
    const float* C = (const float*)d_in[0];
    float* out = (float*)d_out;
    dp_softmin_wave<<<512, 64, 0, stream>>>(C, out);
}

// Round 5
// 116.674 us; speedup vs baseline: 1.6575x; 1.2339x over previous
//
#include <hip/hip_runtime.h>

#define S 256
#define BIGE 1.0e9f              // BIG in E(log2) domain; only role: exp2(m-x) -> 0
#define L2E 1.44269504088896340736f   // log2(e)
#define LN2 0.69314718055994530942f

// Raw HW transcendentals: v_exp_f32 = 2^x, v_log_f32 = log2(x).
#define EXP2F(x) __builtin_amdgcn_exp2f(x)
#define LOG2F(x) __builtin_amdgcn_logf(x)

// One wave (64 threads) per batch, thread t owns rows 4t..4t+3.
// ALL state in named registers (no arrays -> nothing can demote to scratch):
//   c0..c3 : current C quad per row (float4 covering columns [q, q+4))
//   n0..n3 : next quad  [q+4, q+8)
//   x0..x3 : next-next  [q+8, q+12)   (8-diagonal prefetch slack)
//   d10..d13 / d20..d23 : DP values on diag k-1 / k-2 for rows 4t..4t+3
// Cross-thread neighbor (row 4t-1) via 2x __shfl_up; no LDS, no barriers.
// E-domain DP: E = D*log2(e);  E = C*L2E + m - log2(2^(m-a)+2^(m-b)+2^(m-c)).

template <int I> __device__ __forceinline__ float comp(const float4& v) {
    if constexpr (I == 0) return v.x;
    else if constexpr (I == 1) return v.y;
    else if constexpr (I == 2) return v.z;
    else return v.w;
}

__device__ __forceinline__ float cell(float a, float b, float c, float cE, bool valid) {
    float m = fminf(fminf(a, b), c);
    float s = EXP2F(m - a) + EXP2F(m - b) + EXP2F(m - c);
    float v = cE + m - LOG2F(s);
    return valid ? v : BIGE;
}

template <int P>
__device__ __forceinline__ void stepf(
    int kk, int t, const float* __restrict__ Cb, int o0,
    float4& c0, float4& c1, float4& c2, float4& c3,
    float4& n0, float4& n1, float4& n2, float4& n3,
    float4& x0, float4& x1, float4& x2, float4& x3,
    float& d10, float& d11, float& d12, float& d13,
    float& d20, float& d21, float& d22, float& d23)
{
    float pd1 = __shfl_up(d13, 1);
    float pd2 = __shfl_up(d23, 1);
    if (t == 0) { pd1 = BIGE; pd2 = BIGE; }

    const int t4 = 4 * t;
    const int jp = kk - t4 - P;            // designated row P's column (multiple of 4)

    // rotate row P's quad pipeline + prefetch 2 quads ahead
    float4& cP = (P == 0) ? c0 : (P == 1) ? c1 : (P == 2) ? c2 : c3;
    float4& nP = (P == 0) ? n0 : (P == 1) ? n1 : (P == 2) ? n2 : n3;
    float4& xP = (P == 0) ? x0 : (P == 1) ? x1 : (P == 2) ? x2 : x3;
    if (jp > 0 && jp < S) { cP = nP; nP = xP; }
    if (jp > 0 && jp <= S - 12) {
        // &C[row P][jp+8] = Cb + o0 + 255*P + kk   (o0 = 1020*t + 8)
        xP = *(const float4*)(Cb + o0 + 255 * P + kk);
    }

    const int j0 = kk - t4;
    float e0 = cell(d10, pd1, pd2, comp<(P    ) & 3>(c0) * L2E, (j0     >= 0) && (j0     < S));
    float e1 = cell(d11, d10, d20, comp<(P + 3) & 3>(c1) * L2E, (j0 - 1 >= 0) && (j0 - 1 < S));
    float e2 = cell(d12, d11, d21, comp<(P + 2) & 3>(c2) * L2E, (j0 - 2 >= 0) && (j0 - 2 < S));
    float e3 = cell(d13, d12, d22, comp<(P + 1) & 3>(c3) * L2E, (j0 - 3 >= 0) && (j0 - 3 < S));

    d20 = d10; d21 = d11; d22 = d12; d23 = d13;
    d10 = e0;  d11 = e1;  d12 = e2;  d13 = e3;
}

__global__ __launch_bounds__(64) void dp_softmin_wave(const float* __restrict__ C,
                                                      float* __restrict__ out) {
    const int b = blockIdx.x;
    const int t = threadIdx.x;
    const float* Cb = C + ((size_t)b << 16);
    const int t4 = 4 * t;
    const int o0 = 1020 * t + 8;           // lane-invariant load offset base

    const float* R0 = Cb + ((size_t)(t4 + 0) << 8);
    const float* R1 = Cb + ((size_t)(t4 + 1) << 8);
    const float* R2 = Cb + ((size_t)(t4 + 2) << 8);
    const float* R3 = Cb + ((size_t)(t4 + 3) << 8);

    float4 c0 = *(const float4*)(R0),     c1 = *(const float4*)(R1),
           c2 = *(const float4*)(R2),     c3 = *(const float4*)(R3);
    float4 n0 = *(const float4*)(R0 + 4), n1 = *(const float4*)(R1 + 4),
           n2 = *(const float4*)(R2 + 4), n3 = *(const float4*)(R3 + 4);
    float4 x0 = *(const float4*)(R0 + 8), x1 = *(const float4*)(R1 + 8),
           x2 = *(const float4*)(R2 + 8), x3 = *(const float4*)(R3 + 8);

    float d10 = BIGE, d11 = BIGE, d12 = BIGE, d13 = BIGE;
    float d20 = BIGE, d21 = BIGE, d22 = BIGE, d23 = BIGE;

    if (t == 0) d10 = c0.x * L2E;          // seed D[0][0] = C[0][0]

#define ARGS t, Cb, o0, c0,c1,c2,c3, n0,n1,n2,n3, x0,x1,x2,x3, \
             d10,d11,d12,d13, d20,d21,d22,d23

    stepf<1>(1, ARGS);
    stepf<2>(2, ARGS);
    stepf<3>(3, ARGS);
    for (int kb = 4; kb <= 504; kb += 4) {
        stepf<0>(kb + 0, ARGS);
        stepf<1>(kb + 1, ARGS);
        stepf<2>(kb + 2, ARGS);
        stepf<3>(kb + 3, ARGS);
    }
    stepf<0>(508, ARGS);
    stepf<1>(509, ARGS);
    stepf<2>(510, ARGS);
#undef ARGS

    // D[255][255] is thread 63's d13 (E-domain)
    if (t == 63) out[b] = d13 * LN2;
}

extern "C" void kernel_launch(void* const* d_in, const int* in_sizes, int n_in,
                              void* d_out, int out_size, void* d_ws, size_t ws_size,
                              hipStream_t stream) {
    const float* C = (const float*)d_in[0];
    float* out = (float*)d_out;
    dp_softmin_wave<<<512, 64, 0, stream>>>(C, out);
}